// Round 14
// baseline (1078.537 us; speedup 1.0000x reference)
//
#include <hip/hip_runtime.h>

#define B_N 16384
#define G_N 8192
#define D_N 1024
#define NT 48   // virtual K = 3072 = 48 K-tiles of 64 (0-15 hi.hi, 16-31 lo.hi, 32-47 hi.lo)

typedef unsigned short u16;
typedef unsigned long long u64;
typedef __attribute__((ext_vector_type(8))) short short8;
typedef __attribute__((ext_vector_type(16))) float f32x16;

#define AS1 __attribute__((address_space(1)))
#define AS3 __attribute__((address_space(3)))

// ======================= common small kernels =======================

__global__ __launch_bounds__(256) void k_norms(const float* __restrict__ g,
                                               float* __restrict__ invn) {
    const int j = blockIdx.x;
    const int t = threadIdx.x;
    const float4 v = *reinterpret_cast<const float4*>(&g[(size_t)j * D_N + t * 4]);
    float s = v.x * v.x + v.y * v.y + v.z * v.z + v.w * v.w;
#pragma unroll
    for (int off = 32; off >= 1; off >>= 1) s += __shfl_down(s, off, 64);
    __shared__ float wsum[4];
    if ((t & 63) == 0) wsum[t >> 6] = s;
    __syncthreads();
    if (t == 0) {
        const float tot = wsum[0] + wsum[1] + wsum[2] + wsum[3];
        invn[j] = 1.0f / fmaxf(sqrtf(tot), 1e-12f);
    }
}

__global__ void k_counts(const u64* __restrict__ pk, int* __restrict__ counts) {
    const int i = blockIdx.x * blockDim.x + threadIdx.x;
    if (i < B_N) {
        const int a = 8191 - (int)(pk[i] & 0x1FFFull);
        atomicAdd(&counts[a], 1);
    }
}

__global__ __launch_bounds__(256) void k_scatter(const float* __restrict__ x,
                                                 const u64* __restrict__ pk,
                                                 const int* __restrict__ counts,
                                                 float* __restrict__ contrib) {
    const int i = blockIdx.x;
    const int a = 8191 - (int)(pk[i] & 0x1FFFull);
    const float scale = 1.0f / (float)counts[a];
    const int t = threadIdx.x;
    const float4 v = *reinterpret_cast<const float4*>(&x[(size_t)i * D_N + t * 4]);
    float* dst = &contrib[(size_t)a * D_N + t * 4];
    atomicAdd(dst + 0, v.x * scale);
    atomicAdd(dst + 1, v.y * scale);
    atomicAdd(dst + 2, v.z * scale);
    atomicAdd(dst + 3, v.w * scale);
}

__global__ __launch_bounds__(256) void k_finalize(const float* __restrict__ g,
                                                  const int* __restrict__ counts,
                                                  float* __restrict__ out) {
    const int j = blockIdx.x;
    const int t = threadIdx.x;
    const float sc = (counts[j] > 0) ? 0.99f : 1.0f;
    const float4 gv = *reinterpret_cast<const float4*>(&g[(size_t)j * D_N + t * 4]);
    const float4 cv = *reinterpret_cast<const float4*>(&out[(size_t)j * D_N + t * 4]);
    float4 gf;
    gf.x = sc * gv.x + 0.01f * cv.x;
    gf.y = sc * gv.y + 0.01f * cv.y;
    gf.z = sc * gv.z + 0.01f * cv.z;
    gf.w = sc * gv.w + 0.01f * cv.w;
    float s = gf.x * gf.x + gf.y * gf.y + gf.z * gf.z + gf.w * gf.w;
#pragma unroll
    for (int off = 32; off >= 1; off >>= 1) s += __shfl_down(s, off, 64);
    __shared__ float wsum[4];
    __shared__ float s_inv;
    if ((t & 63) == 0) wsum[t >> 6] = s;
    __syncthreads();
    if (t == 0) s_inv = 1.0f / fmaxf(sqrtf(wsum[0] + wsum[1] + wsum[2] + wsum[3]), 1e-12f);
    __syncthreads();
    gf.x *= s_inv; gf.y *= s_inv; gf.z *= s_inv; gf.w *= s_inv;
    *reinterpret_cast<float4*>(&out[(size_t)j * D_N + t * 4]) = gf;
}

// ======================= bf16 split + fragment-brick pack =======================
// brick(mu,tau) = rows [mu*32,+32) x k [tau*32,+32), 2KB; chunk c: ks=c>>6,
// lane=c&63 -> row=mu*32+(lane&31), k=tau*32+ks*16+(lane>>5)*8, 16B contiguous.
// Staging reads consecutive 16B chunks (perfect coalescing) into LINEAR LDS;
// MFMA fragment reads are contiguous 1KiB per wave (0 bank conflicts, measured R6).

__device__ inline u16 f2bf_rtn(float f) {
    unsigned u = __float_as_uint(f);
    unsigned r = u + 0x7fffu + ((u >> 16) & 1u);
    return (u16)(r >> 16);
}
__device__ inline float bf2f(u16 h) { return __uint_as_float(((unsigned)h) << 16); }

__global__ __launch_bounds__(256) void k_split_pack(const float* __restrict__ src,
                                                    u16* __restrict__ hi,
                                                    u16* __restrict__ lo) {
    const int id = blockIdx.x * 256 + threadIdx.x;    // packed chunk id
    const int brick = id >> 7, c = id & 127;
    const int mu = brick >> 5, tau = brick & 31;
    const int ks = c >> 6, lane = c & 63;
    const int row = mu * 32 + (lane & 31);
    const int k = tau * 32 + ks * 16 + (lane >> 5) * 8;
    const float* s = src + (size_t)row * D_N + k;
    const float4 v0 = *reinterpret_cast<const float4*>(s);
    const float4 v1 = *reinterpret_cast<const float4*>(s + 4);
    const float f[8] = {v0.x, v0.y, v0.z, v0.w, v1.x, v1.y, v1.z, v1.w};
    short8 h, l;
#pragma unroll
    for (int j = 0; j < 8; ++j) {
        const u16 hj = f2bf_rtn(f[j]);
        h[j] = (short)hj;
        l[j] = (short)f2bf_rtn(f[j] - bf2f(hj));
    }
    *reinterpret_cast<short8*>(hi + (size_t)id * 8) = h;
    *reinterpret_cast<short8*>(lo + (size_t)id * 8) = l;
}

// ======================= BK=64 4-wave 256x256 MFMA GEMM + fused argmax ==================
// mfma_f32_32x32x16_bf16, 4 waves (2x2), per-wave C 128x128 (16 acc frags).
// BK=64 -> 48 bodies (HALF the per-body overhead events of BK=32 variants; R5-R12
// showed body time = MFMA + port + ~1.2k cyc fixed overhead regardless of schedule,
// so fewer, bigger bodies amortize the fixed term).
// LDS 128KB = 2 bufs x (A 32KB + B 32KB), fragment-brick order (linear).
// Body q = { STG(q+1) 16 glds -> buf (q+1)&1; READS(q) 32 ds_read_b128 from buf q&1
//            in consumption order (compiler emits fine-grained lgkm -> first MFMA
//            starts after 8 reads); MFMA(q) 64x; vmcnt(0) [glds ~2k cyc old, cheap
//            -- R6 measured drain==counted]; s_barrier }.

#define MFMA_BLK() do {                                                                    \
    __builtin_amdgcn_s_setprio(1);                                                         \
    _Pragma("unroll")                                                                      \
    for (int k4 = 0; k4 < 4; ++k4)                                                         \
        _Pragma("unroll")                                                                  \
        for (int m = 0; m < 4; ++m)                                                        \
            _Pragma("unroll")                                                              \
            for (int n = 0; n < 4; ++n)                                                    \
                acc[m][n] = __builtin_amdgcn_mfma_f32_32x32x16_bf16(                       \
                    afr[m][k4], bfr[n][k4], acc[m][n], 0, 0, 0);                           \
    __builtin_amdgcn_s_setprio(0);                                                         \
} while (0)

// consumption order: per k4 block, B frags then A frags
#define READS(BUF) do {                                                                    \
    const u16* aB = lds + (BUF) * 32768 + wr * 8192 + lane * 8;                            \
    const u16* bB = lds + (BUF) * 32768 + 16384 + wc * 8192 + lane * 8;                    \
    _Pragma("unroll")                                                                      \
    for (int k4 = 0; k4 < 4; ++k4) {                                                       \
        const int ko = (k4 >> 1) * 1024 + (k4 & 1) * 512;                                  \
        _Pragma("unroll")                                                                  \
        for (int n = 0; n < 4; ++n)                                                        \
            bfr[n][k4] = *reinterpret_cast<const short8*>(bB + n * 2048 + ko);             \
        _Pragma("unroll")                                                                  \
        for (int m = 0; m < 4; ++m)                                                        \
            afr[m][k4] = *reinterpret_cast<const short8*>(aB + m * 2048 + ko);             \
    }                                                                                      \
} while (0)

#define BODY(Q, BSTG, BRD) do {                                                            \
    STG((Q) + 1, BSTG);                                                                    \
    READS(BRD);                                                                            \
    MFMA_BLK();                                                                            \
    asm volatile("s_waitcnt vmcnt(0)" ::: "memory");                                       \
    __builtin_amdgcn_s_barrier();                                                          \
} while (0)

__global__ __launch_bounds__(256, 1) void k_gemm_argmax(
    const u16* __restrict__ x_hi, const u16* __restrict__ x_lo,
    const u16* __restrict__ g_hi, const u16* __restrict__ g_lo,
    const float* __restrict__ invn, u64* __restrict__ pk) {

    __shared__ __align__(16) u16 lds[65536];   // 128 KiB: 2 bufs x 64KB (A 32 + B 32)

    const int bid = blockIdx.x;                // 2048 blocks
    const int xcd = bid & 7, lcl = bid >> 3;
    const int mblk = xcd * 8 + ((lcl >> 3) & 7);
    const int nblk = (lcl & 7) + (lcl >> 6) * 8;   // 4x8 patches resident per XCD
    const int mrow0 = mblk * 256, nrow0 = nblk * 256;

    const int tid = threadIdx.x;               // 256 threads = 4 waves
    const int lane = tid & 63;
    const int w = tid >> 6;
    const int wr = w >> 1, wc = w & 1;         // 2x2 wave grid, per-wave C = 128x128
    const int l31 = lane & 31, l5 = lane >> 5;

    // staging: thread stages chunk c = tid + i*256, i=0..7, for A and B (16 glds/thread-slot)
    // c -> brick b=(tid>>7)+2i (mu=i, tau=tid>>7), within-brick chunk cw=tid&127.
    const int hb = tid >> 7;
    const size_t aOff0 = (size_t)mblk * 262144 + hb * 1024 + (tid & 127) * 8;
    const size_t bOff0 = (size_t)nblk * 262144 + hb * 1024 + (tid & 127) * 8;
    const int dW = w * 512;                    // wave-uniform LDS dest base (u16)

    auto STG = [&](int T, int buf) {
        const int Tc = T < NT ? T : NT - 1;    // clamp: rewrite into the retired buffer, benign
        const int term = Tc >> 4;
        const size_t tko = (size_t)(Tc & 15) * 2048;   // (ktile)*2 bricks * 1024 u16
        const u16* xa = ((term == 1) ? x_lo : x_hi) + aOff0 + tko;
        const u16* gb = ((term == 2) ? g_lo : g_hi) + bOff0 + tko;
        u16* da = lds + buf * 32768 + dW;
        u16* db = da + 16384;
#pragma unroll
        for (int i = 0; i < 8; ++i)
            __builtin_amdgcn_global_load_lds((const AS1 void*)(xa + (size_t)i * 32768),
                                             (AS3 void*)(da + i * 2048), 16, 0, 0);
#pragma unroll
        for (int i = 0; i < 8; ++i)
            __builtin_amdgcn_global_load_lds((const AS1 void*)(gb + (size_t)i * 32768),
                                             (AS3 void*)(db + i * 2048), 16, 0, 0);
    };

    f32x16 acc[4][4];
#pragma unroll
    for (int m = 0; m < 4; ++m)
#pragma unroll
        for (int n = 0; n < 4; ++n)
#pragma unroll
            for (int r = 0; r < 16; ++r) acc[m][n][r] = 0.0f;

    short8 afr[4][4], bfr[4][4];               // single fragment set (32 b128 regs)

    // prologue: stage tile 0; drain; barrier
    STG(0, 0);
    asm volatile("s_waitcnt vmcnt(0)" ::: "memory");
    __builtin_amdgcn_s_barrier();

    for (int it = 0; it < 24; ++it) {
        const int q = it * 2;
        // body q: STG(q+1) -> buf (q+1)&1; READS(q) from buf q&1; MFMA(q)
        BODY(q,     1, 0);
        BODY(q + 1, 0, 1);
    }

    // ---------- epilogue: invn-scale + packed argmax -> atomicMax ----------
    float inv[4];
#pragma unroll
    for (int n = 0; n < 4; ++n) inv[n] = invn[nrow0 + wc * 128 + n * 32 + l31];

#pragma unroll
    for (int m = 0; m < 4; ++m) {
#pragma unroll
        for (int r = 0; r < 16; ++r) {
            u64 p = 0;
#pragma unroll
            for (int n = 0; n < 4; ++n) {
                const float v = acc[m][n][r] * inv[n];
                unsigned u = __float_as_uint(v);
                u ^= (u >> 31) ? 0xFFFFFFFFu : 0x80000000u;   // monotone float->uint
                const int col = nrow0 + wc * 128 + n * 32 + l31;
                const u64 cand = ((u64)u << 13) | (unsigned)(8191 - col);  // ties -> smaller col
                p = (cand > p) ? cand : p;
            }
#pragma unroll
            for (int msk = 1; msk < 32; msk <<= 1) {
                const u64 o = __shfl_xor(p, msk, 64);
                p = (o > p) ? o : p;
            }
            if (l31 == 0) {
                const int row = mrow0 + wr * 128 + m * 32 + (r & 3) + 8 * (r >> 2) + 4 * l5;
                atomicMax(&pk[row], p);
            }
        }
    }
}

// ======================= fallback fp32 argmax (tiny-ws path) =======================

__global__ __launch_bounds__(256) void k_argmax_fp32(const float* __restrict__ x,
                                                     const float* __restrict__ g,
                                                     const float* __restrict__ invn,
                                                     int* __restrict__ assign) {
    __shared__ __align__(16) float As[32][68];
    __shared__ __align__(16) float Bs[32][68];
    const int t = threadIdx.x;
    const int tx = t & 15;
    const int ty = t >> 4;
    const int row0 = blockIdx.x * 64;
    const int r_a = t >> 3;
    const int c4 = t & 7;
    float bestv[4]; int besti[4];
#pragma unroll
    for (int i = 0; i < 4; ++i) { bestv[i] = -3.0e38f; besti[i] = 0; }
    for (int jt = 0; jt < G_N / 64; ++jt) {
        float acc[4][4] = {};
        for (int kt = 0; kt < D_N / 32; ++kt) {
#pragma unroll
            for (int p = 0; p < 2; ++p) {
                const int r = r_a + p * 32;
                const float4 va = *reinterpret_cast<const float4*>(&x[(size_t)(row0 + r) * D_N + kt * 32 + c4 * 4]);
                As[c4 * 4 + 0][r] = va.x; As[c4 * 4 + 1][r] = va.y; As[c4 * 4 + 2][r] = va.z; As[c4 * 4 + 3][r] = va.w;
                const float4 vb = *reinterpret_cast<const float4*>(&g[(size_t)(jt * 64 + r) * D_N + kt * 32 + c4 * 4]);
                Bs[c4 * 4 + 0][r] = vb.x; Bs[c4 * 4 + 1][r] = vb.y; Bs[c4 * 4 + 2][r] = vb.z; Bs[c4 * 4 + 3][r] = vb.w;
            }
            __syncthreads();
#pragma unroll
            for (int k = 0; k < 32; ++k) {
                const float4 a = *reinterpret_cast<const float4*>(&As[k][ty * 4]);
                const float4 b = *reinterpret_cast<const float4*>(&Bs[k][tx * 4]);
                const float av[4] = {a.x, a.y, a.z, a.w};
                const float bv[4] = {b.x, b.y, b.z, b.w};
#pragma unroll
                for (int i = 0; i < 4; ++i)
#pragma unroll
                    for (int jj = 0; jj < 4; ++jj) acc[i][jj] += av[i] * bv[jj];
            }
            __syncthreads();
        }
#pragma unroll
        for (int jj = 0; jj < 4; ++jj) {
            const int col = jt * 64 + tx * 4 + jj;
            const float s = invn[col];
#pragma unroll
            for (int i = 0; i < 4; ++i) {
                const float v = acc[i][jj] * s;
                if (v > bestv[i]) { bestv[i] = v; besti[i] = col; }
            }
        }
    }
#pragma unroll
    for (int m = 1; m < 16; m <<= 1) {
#pragma unroll
        for (int i = 0; i < 4; ++i) {
            const float ov = __shfl_xor(bestv[i], m, 64);
            const int oi = __shfl_xor(besti[i], m, 64);
            if (ov > bestv[i] || (ov == bestv[i] && oi < besti[i])) { bestv[i] = ov; besti[i] = oi; }
        }
    }
    if (tx == 0) {
#pragma unroll
        for (int i = 0; i < 4; ++i) assign[row0 + ty * 4 + i] = besti[i];
    }
}

__global__ void k_counts_i(const int* __restrict__ assign, int* __restrict__ counts) {
    const int i = blockIdx.x * blockDim.x + threadIdx.x;
    if (i < B_N) atomicAdd(&counts[assign[i]], 1);
}

__global__ __launch_bounds__(256) void k_scatter_i(const float* __restrict__ x,
                                                   const int* __restrict__ assign,
                                                   const int* __restrict__ counts,
                                                   float* __restrict__ contrib) {
    const int i = blockIdx.x;
    const int a = assign[i];
    const float scale = 1.0f / (float)counts[a];
    const int t = threadIdx.x;
    const float4 v = *reinterpret_cast<const float4*>(&x[(size_t)i * D_N + t * 4]);
    float* dst = &contrib[(size_t)a * D_N + t * 4];
    atomicAdd(dst + 0, v.x * scale);
    atomicAdd(dst + 1, v.y * scale);
    atomicAdd(dst + 2, v.z * scale);
    atomicAdd(dst + 3, v.w * scale);
}

// ======================= launch =======================

extern "C" void kernel_launch(void* const* d_in, const int* in_sizes, int n_in,
                              void* d_out, int out_size, void* d_ws, size_t ws_size,
                              hipStream_t stream) {
    const float* x = (const float*)d_in[0];   // [16384, 1024]
    const float* g = (const float*)d_in[1];   // [8192, 1024]
    float* out = (float*)d_out;               // [8192, 1024]; doubles as contrib accumulator

    char* ws = (char*)d_ws;
    u16*  x_hi  = (u16*)(ws);                     // 32 MiB (packed bricks)
    u16*  x_lo  = (u16*)(ws + 33554432);          // 32 MiB
    u16*  g_hi  = (u16*)(ws + 67108864);          // 16 MiB
    u16*  g_lo  = (u16*)(ws + 83886080);          // 16 MiB
    float* invn = (float*)(ws + 100663296);       // 32 KiB
    int* counts = (int*)(ws + 100696064);         // 32 KiB
    u64*   pk   = (u64*)(ws + 100728832);         // 128 KiB packed (value|col) per row
    const size_t need = 100859904;

    hipMemsetAsync(out, 0, (size_t)G_N * D_N * sizeof(float), stream);

    if (ws_size >= need) {
        hipMemsetAsync(counts, 0, (size_t)G_N * sizeof(int), stream);
        hipMemsetAsync(pk, 0, (size_t)B_N * sizeof(u64), stream);
        k_norms<<<G_N, 256, 0, stream>>>(g, invn);
        k_split_pack<<<B_N * D_N / 8 / 256, 256, 0, stream>>>(x, x_hi, x_lo);
        k_split_pack<<<G_N * D_N / 8 / 256, 256, 0, stream>>>(g, g_hi, g_lo);
        k_gemm_argmax<<<2048, 256, 0, stream>>>(x_hi, x_lo, g_hi, g_lo, invn, pk);
        k_counts<<<B_N / 256, 256, 0, stream>>>(pk, counts);
        k_scatter<<<B_N, 256, 0, stream>>>(x, pk, counts, out);
        k_finalize<<<G_N, 256, 0, stream>>>(g, counts, out);
    } else {
        // fallback: fp32 vector path (128 KiB scratch)
        float* invn_f = (float*)ws;
        int* assign_f = (int*)(ws + (size_t)G_N * 4);
        int* counts_f = (int*)(ws + (size_t)(G_N + B_N) * 4);
        hipMemsetAsync(counts_f, 0, (size_t)G_N * sizeof(int), stream);
        k_norms<<<G_N, 256, 0, stream>>>(g, invn_f);
        k_argmax_fp32<<<B_N / 64, 256, 0, stream>>>(x, g, invn_f, assign_f);
        k_counts_i<<<B_N / 256, 256, 0, stream>>>(assign_f, counts_f);
        k_scatter_i<<<B_N, 256, 0, stream>>>(x, assign_f, counts_f, out);
        k_finalize<<<G_N, 256, 0, stream>>>(g, counts_f, out);
    }
}

// Round 15
// 987.330 us; speedup vs baseline: 1.0924x; 1.0924x over previous
//
#include <hip/hip_runtime.h>

#define B_N 16384
#define G_N 8192
#define D_N 1024
#define NT 96   // virtual K = 3072 = 96 K-tiles of 32 (0-31 hi.hi, 32-63 lo.hi, 64-95 hi.lo)

typedef unsigned short u16;
typedef unsigned long long u64;
typedef __attribute__((ext_vector_type(8))) short short8;
typedef __attribute__((ext_vector_type(16))) float f32x16;

// ======================= common small kernels =======================

__global__ __launch_bounds__(256) void k_norms(const float* __restrict__ g,
                                               float* __restrict__ invn) {
    const int j = blockIdx.x;
    const int t = threadIdx.x;
    const float4 v = *reinterpret_cast<const float4*>(&g[(size_t)j * D_N + t * 4]);
    float s = v.x * v.x + v.y * v.y + v.z * v.z + v.w * v.w;
#pragma unroll
    for (int off = 32; off >= 1; off >>= 1) s += __shfl_down(s, off, 64);
    __shared__ float wsum[4];
    if ((t & 63) == 0) wsum[t >> 6] = s;
    __syncthreads();
    if (t == 0) {
        const float tot = wsum[0] + wsum[1] + wsum[2] + wsum[3];
        invn[j] = 1.0f / fmaxf(sqrtf(tot), 1e-12f);
    }
}

__global__ void k_counts(const u64* __restrict__ pk, int* __restrict__ counts) {
    const int i = blockIdx.x * blockDim.x + threadIdx.x;
    if (i < B_N) {
        const int a = 8191 - (int)(pk[i] & 0x1FFFull);
        atomicAdd(&counts[a], 1);
    }
}

__global__ __launch_bounds__(256) void k_scatter(const float* __restrict__ x,
                                                 const u64* __restrict__ pk,
                                                 const int* __restrict__ counts,
                                                 float* __restrict__ contrib) {
    const int i = blockIdx.x;
    const int a = 8191 - (int)(pk[i] & 0x1FFFull);
    const float scale = 1.0f / (float)counts[a];
    const int t = threadIdx.x;
    const float4 v = *reinterpret_cast<const float4*>(&x[(size_t)i * D_N + t * 4]);
    float* dst = &contrib[(size_t)a * D_N + t * 4];
    atomicAdd(dst + 0, v.x * scale);
    atomicAdd(dst + 1, v.y * scale);
    atomicAdd(dst + 2, v.z * scale);
    atomicAdd(dst + 3, v.w * scale);
}

__global__ __launch_bounds__(256) void k_finalize(const float* __restrict__ g,
                                                  const int* __restrict__ counts,
                                                  float* __restrict__ out) {
    const int j = blockIdx.x;
    const int t = threadIdx.x;
    const float sc = (counts[j] > 0) ? 0.99f : 1.0f;
    const float4 gv = *reinterpret_cast<const float4*>(&g[(size_t)j * D_N + t * 4]);
    const float4 cv = *reinterpret_cast<const float4*>(&out[(size_t)j * D_N + t * 4]);
    float4 gf;
    gf.x = sc * gv.x + 0.01f * cv.x;
    gf.y = sc * gv.y + 0.01f * cv.y;
    gf.z = sc * gv.z + 0.01f * cv.z;
    gf.w = sc * gv.w + 0.01f * cv.w;
    float s = gf.x * gf.x + gf.y * gf.y + gf.z * gf.z + gf.w * gf.w;
#pragma unroll
    for (int off = 32; off >= 1; off >>= 1) s += __shfl_down(s, off, 64);
    __shared__ float wsum[4];
    __shared__ float s_inv;
    if ((t & 63) == 0) wsum[t >> 6] = s;
    __syncthreads();
    if (t == 0) s_inv = 1.0f / fmaxf(sqrtf(wsum[0] + wsum[1] + wsum[2] + wsum[3]), 1e-12f);
    __syncthreads();
    gf.x *= s_inv; gf.y *= s_inv; gf.z *= s_inv; gf.w *= s_inv;
    *reinterpret_cast<float4*>(&out[(size_t)j * D_N + t * 4]) = gf;
}

// ======================= bf16 split + fragment-brick pack =======================
// brick(mu,tau) = rows [mu*32,+32) x k [tau*32,+32), 2KB; chunk c: ks=c>>6,
// lane=c&63 -> row=mu*32+(lane&31), k=tau*32+ks*16+(lane>>5)*8, 16B contiguous.
// A fragment for mfma_32x32x16 == chunks [ks*64, ks*64+64) of one brick ==
// one 64-lane x 16B perfectly-coalesced global load -> fragments load DIRECTLY
// global->VGPR, no LDS round trip at all.

__device__ inline u16 f2bf_rtn(float f) {
    unsigned u = __float_as_uint(f);
    unsigned r = u + 0x7fffu + ((u >> 16) & 1u);
    return (u16)(r >> 16);
}
__device__ inline float bf2f(u16 h) { return __uint_as_float(((unsigned)h) << 16); }

__global__ __launch_bounds__(256) void k_split_pack(const float* __restrict__ src,
                                                    u16* __restrict__ hi,
                                                    u16* __restrict__ lo) {
    const int id = blockIdx.x * 256 + threadIdx.x;    // packed chunk id
    const int brick = id >> 7, c = id & 127;
    const int mu = brick >> 5, tau = brick & 31;
    const int ks = c >> 6, lane = c & 63;
    const int row = mu * 32 + (lane & 31);
    const int k = tau * 32 + ks * 16 + (lane >> 5) * 8;
    const float* s = src + (size_t)row * D_N + k;
    const float4 v0 = *reinterpret_cast<const float4*>(s);
    const float4 v1 = *reinterpret_cast<const float4*>(s + 4);
    const float f[8] = {v0.x, v0.y, v0.z, v0.w, v1.x, v1.y, v1.z, v1.w};
    short8 h, l;
#pragma unroll
    for (int j = 0; j < 8; ++j) {
        const u16 hj = f2bf_rtn(f[j]);
        h[j] = (short)hj;
        l[j] = (short)f2bf_rtn(f[j] - bf2f(hj));
    }
    *reinterpret_cast<short8*>(hi + (size_t)id * 8) = h;
    *reinterpret_cast<short8*>(lo + (size_t)id * 8) = l;
}

// ======================= barrier-free direct-load MFMA GEMM + fused argmax ==============
// mfma_f32_32x32x16_bf16, 4 waves (2x2), per-wave C 128x128 (16 acc frags). NO LDS,
// NO barriers, NO manual waitcnt in the K-loop. Fragments load directly global->VGPR
// (brick layout == fragment layout, coalesced 1KB/load, L2-resident panels).
// R5-R13 post-mortem: every LDS-staged barrier-locked schedule serialized LDS-port
// time with MFMA time (38-45% MfmaUtil across 9 variants) because barriers keep all
// waves in the same phase. Here the 4 waves are fully independent: loads of tile q+1
// (compiler-tracked counted vmcnt) overlap MFMA of tile q within the wave, and waves
// de-phase naturally so vector-memory service overlaps other waves' MFMA bursts.

#define MFMA_BLK(S) do {                                                                   \
    __builtin_amdgcn_s_setprio(1);                                                         \
    _Pragma("unroll")                                                                      \
    for (int ks = 0; ks < 2; ++ks)                                                         \
        _Pragma("unroll")                                                                  \
        for (int m = 0; m < 4; ++m)                                                        \
            _Pragma("unroll")                                                              \
            for (int n = 0; n < 4; ++n)                                                    \
                acc[m][n] = __builtin_amdgcn_mfma_f32_32x32x16_bf16(                       \
                    afr[S][m][ks], bfr[S][n][ks], acc[m][n], 0, 0, 0);                     \
    __builtin_amdgcn_s_setprio(0);                                                         \
} while (0)

#define LOADG(T, S) do {                                                                   \
    const int Tc_ = (T) < NT ? (T) : NT - 1;                                               \
    const u16* xa_ = ((Tc_ >> 5) == 1) ? x_lo : x_hi;                                      \
    const u16* gb_ = ((Tc_ >> 5) == 2) ? g_lo : g_hi;                                      \
    const size_t tk_ = (size_t)(Tc_ & 31) * 1024 + laneOff;                                \
    _Pragma("unroll")                                                                      \
    for (int m = 0; m < 4; ++m)                                                            \
        _Pragma("unroll")                                                                  \
        for (int ks = 0; ks < 2; ++ks)                                                     \
            afr[S][m][ks] = *reinterpret_cast<const short8*>(xa_ + aBr[m] + tk_ + ks * 512);\
    _Pragma("unroll")                                                                      \
    for (int n = 0; n < 4; ++n)                                                            \
        _Pragma("unroll")                                                                  \
        for (int ks = 0; ks < 2; ++ks)                                                     \
            bfr[S][n][ks] = *reinterpret_cast<const short8*>(gb_ + bBr[n] + tk_ + ks * 512);\
} while (0)

__global__ __launch_bounds__(256, 1) void k_gemm_argmax(
    const u16* __restrict__ x_hi, const u16* __restrict__ x_lo,
    const u16* __restrict__ g_hi, const u16* __restrict__ g_lo,
    const float* __restrict__ invn, u64* __restrict__ pk) {

    const int bid = blockIdx.x;                // 2048 blocks
    const int xcd = bid & 7, lcl = bid >> 3;
    const int mblk = xcd * 8 + ((lcl >> 3) & 7);
    const int nblk = (lcl & 7) + (lcl >> 6) * 8;   // 4x8 patches resident per XCD
    const int mrow0 = mblk * 256, nrow0 = nblk * 256;

    const int tid = threadIdx.x;               // 256 threads = 4 waves
    const int lane = tid & 63;
    const int w = tid >> 6;
    const int wr = w >> 1, wc = w & 1;         // 2x2 wave grid, per-wave C = 128x128
    const int l31 = lane & 31, l5 = lane >> 5;

    // per-wave brick bases (u16 offsets): brick(mu,tau) @ (mu*32+tau)*1024
    const size_t laneOff = (size_t)lane * 8;
    size_t aBr[4], bBr[4];
#pragma unroll
    for (int m = 0; m < 4; ++m) aBr[m] = (size_t)(mblk * 8 + wr * 4 + m) * 32768;
#pragma unroll
    for (int n = 0; n < 4; ++n) bBr[n] = (size_t)(nblk * 8 + wc * 4 + n) * 32768;

    f32x16 acc[4][4];
#pragma unroll
    for (int m = 0; m < 4; ++m)
#pragma unroll
        for (int n = 0; n < 4; ++n)
#pragma unroll
            for (int r = 0; r < 16; ++r) acc[m][n][r] = 0.0f;

    short8 afr[2][4][2], bfr[2][4][2];         // double-buffered fragment sets

    // prologue: load tile 0 fragments
    LOADG(0, 0);

    for (int it = 0; it < 48; ++it) {
        const int q = it * 2;
        LOADG(q + 1, 1);   // loads for next tile (compiler-counted vmcnt)
        MFMA_BLK(0);       // compute current tile - covers load latency
        LOADG(q + 2, 0);
        MFMA_BLK(1);
    }

    // ---------- epilogue: invn-scale + packed argmax -> atomicMax ----------
    float inv[4];
#pragma unroll
    for (int n = 0; n < 4; ++n) inv[n] = invn[nrow0 + wc * 128 + n * 32 + l31];

#pragma unroll
    for (int m = 0; m < 4; ++m) {
#pragma unroll
        for (int r = 0; r < 16; ++r) {
            u64 p = 0;
#pragma unroll
            for (int n = 0; n < 4; ++n) {
                const float v = acc[m][n][r] * inv[n];
                unsigned u = __float_as_uint(v);
                u ^= (u >> 31) ? 0xFFFFFFFFu : 0x80000000u;   // monotone float->uint
                const int col = nrow0 + wc * 128 + n * 32 + l31;
                const u64 cand = ((u64)u << 13) | (unsigned)(8191 - col);  // ties -> smaller col
                p = (cand > p) ? cand : p;
            }
#pragma unroll
            for (int msk = 1; msk < 32; msk <<= 1) {
                const u64 o = __shfl_xor(p, msk, 64);
                p = (o > p) ? o : p;
            }
            if (l31 == 0) {
                const int row = mrow0 + wr * 128 + m * 32 + (r & 3) + 8 * (r >> 2) + 4 * l5;
                atomicMax(&pk[row], p);
            }
        }
    }
}

// ======================= fallback fp32 argmax (tiny-ws path) =======================

__global__ __launch_bounds__(256) void k_argmax_fp32(const float* __restrict__ x,
                                                     const float* __restrict__ g,
                                                     const float* __restrict__ invn,
                                                     int* __restrict__ assign) {
    __shared__ __align__(16) float As[32][68];
    __shared__ __align__(16) float Bs[32][68];
    const int t = threadIdx.x;
    const int tx = t & 15;
    const int ty = t >> 4;
    const int row0 = blockIdx.x * 64;
    const int r_a = t >> 3;
    const int c4 = t & 7;
    float bestv[4]; int besti[4];
#pragma unroll
    for (int i = 0; i < 4; ++i) { bestv[i] = -3.0e38f; besti[i] = 0; }
    for (int jt = 0; jt < G_N / 64; ++jt) {
        float acc[4][4] = {};
        for (int kt = 0; kt < D_N / 32; ++kt) {
#pragma unroll
            for (int p = 0; p < 2; ++p) {
                const int r = r_a + p * 32;
                const float4 va = *reinterpret_cast<const float4*>(&x[(size_t)(row0 + r) * D_N + kt * 32 + c4 * 4]);
                As[c4 * 4 + 0][r] = va.x; As[c4 * 4 + 1][r] = va.y; As[c4 * 4 + 2][r] = va.z; As[c4 * 4 + 3][r] = va.w;
                const float4 vb = *reinterpret_cast<const float4*>(&g[(size_t)(jt * 64 + r) * D_N + kt * 32 + c4 * 4]);
                Bs[c4 * 4 + 0][r] = vb.x; Bs[c4 * 4 + 1][r] = vb.y; Bs[c4 * 4 + 2][r] = vb.z; Bs[c4 * 4 + 3][r] = vb.w;
            }
            __syncthreads();
#pragma unroll
            for (int k = 0; k < 32; ++k) {
                const float4 a = *reinterpret_cast<const float4*>(&As[k][ty * 4]);
                const float4 b = *reinterpret_cast<const float4*>(&Bs[k][tx * 4]);
                const float av[4] = {a.x, a.y, a.z, a.w};
                const float bv[4] = {b.x, b.y, b.z, b.w};
#pragma unroll
                for (int i = 0; i < 4; ++i)
#pragma unroll
                    for (int jj = 0; jj < 4; ++jj) acc[i][jj] += av[i] * bv[jj];
            }
            __syncthreads();
        }
#pragma unroll
        for (int jj = 0; jj < 4; ++jj) {
            const int col = jt * 64 + tx * 4 + jj;
            const float s = invn[col];
#pragma unroll
            for (int i = 0; i < 4; ++i) {
                const float v = acc[i][jj] * s;
                if (v > bestv[i]) { bestv[i] = v; besti[i] = col; }
            }
        }
    }
#pragma unroll
    for (int m = 1; m < 16; m <<= 1) {
#pragma unroll
        for (int i = 0; i < 4; ++i) {
            const float ov = __shfl_xor(bestv[i], m, 64);
            const int oi = __shfl_xor(besti[i], m, 64);
            if (ov > bestv[i] || (ov == bestv[i] && oi < besti[i])) { bestv[i] = ov; besti[i] = oi; }
        }
    }
    if (tx == 0) {
#pragma unroll
        for (int i = 0; i < 4; ++i) assign[row0 + ty * 4 + i] = besti[i];
    }
}

__global__ void k_counts_i(const int* __restrict__ assign, int* __restrict__ counts) {
    const int i = blockIdx.x * blockDim.x + threadIdx.x;
    if (i < B_N) atomicAdd(&counts[assign[i]], 1);
}

__global__ __launch_bounds__(256) void k_scatter_i(const float* __restrict__ x,
                                                   const int* __restrict__ assign,
                                                   const int* __restrict__ counts,
                                                   float* __restrict__ contrib) {
    const int i = blockIdx.x;
    const int a = assign[i];
    const float scale = 1.0f / (float)counts[a];
    const int t = threadIdx.x;
    const float4 v = *reinterpret_cast<const float4*>(&x[(size_t)i * D_N + t * 4]);
    float* dst = &contrib[(size_t)a * D_N + t * 4];
    atomicAdd(dst + 0, v.x * scale);
    atomicAdd(dst + 1, v.y * scale);
    atomicAdd(dst + 2, v.z * scale);
    atomicAdd(dst + 3, v.w * scale);
}

// ======================= launch =======================

extern "C" void kernel_launch(void* const* d_in, const int* in_sizes, int n_in,
                              void* d_out, int out_size, void* d_ws, size_t ws_size,
                              hipStream_t stream) {
    const float* x = (const float*)d_in[0];   // [16384, 1024]
    const float* g = (const float*)d_in[1];   // [8192, 1024]
    float* out = (float*)d_out;               // [8192, 1024]; doubles as contrib accumulator

    char* ws = (char*)d_ws;
    u16*  x_hi  = (u16*)(ws);                     // 32 MiB (packed bricks)
    u16*  x_lo  = (u16*)(ws + 33554432);          // 32 MiB
    u16*  g_hi  = (u16*)(ws + 67108864);          // 16 MiB
    u16*  g_lo  = (u16*)(ws + 83886080);          // 16 MiB
    float* invn = (float*)(ws + 100663296);       // 32 KiB
    int* counts = (int*)(ws + 100696064);         // 32 KiB
    u64*   pk   = (u64*)(ws + 100728832);         // 128 KiB packed (value|col) per row
    const size_t need = 100859904;

    hipMemsetAsync(out, 0, (size_t)G_N * D_N * sizeof(float), stream);

    if (ws_size >= need) {
        hipMemsetAsync(counts, 0, (size_t)G_N * sizeof(int), stream);
        hipMemsetAsync(pk, 0, (size_t)B_N * sizeof(u64), stream);
        k_norms<<<G_N, 256, 0, stream>>>(g, invn);
        k_split_pack<<<B_N * D_N / 8 / 256, 256, 0, stream>>>(x, x_hi, x_lo);
        k_split_pack<<<G_N * D_N / 8 / 256, 256, 0, stream>>>(g, g_hi, g_lo);
        k_gemm_argmax<<<2048, 256, 0, stream>>>(x_hi, x_lo, g_hi, g_lo, invn, pk);
        k_counts<<<B_N / 256, 256, 0, stream>>>(pk, counts);
        k_scatter<<<B_N, 256, 0, stream>>>(x, pk, counts, out);
        k_finalize<<<G_N, 256, 0, stream>>>(g, counts, out);
    } else {
        // fallback: fp32 vector path (128 KiB scratch)
        float* invn_f = (float*)ws;
        int* assign_f = (int*)(ws + (size_t)G_N * 4);
        int* counts_f = (int*)(ws + (size_t)(G_N + B_N) * 4);
        hipMemsetAsync(counts_f, 0, (size_t)G_N * sizeof(int), stream);
        k_norms<<<G_N, 256, 0, stream>>>(g, invn_f);
        k_argmax_fp32<<<B_N / 64, 256, 0, stream>>>(x, g, invn_f, assign_f);
        k_counts_i<<<B_N / 256, 256, 0, stream>>>(assign_f, counts_f);
        k_scatter_i<<<B_N, 256, 0, stream>>>(x, assign_f, counts_f, out);
        k_finalize<<<G_N, 256, 0, stream>>>(g, counts_f, out);
    }
}